// Round 10
// baseline (313.709 us; speedup 1.0000x reference)
//
#include <hip/hip_runtime.h>
#include <hip/hip_fp16.h>

#define F 128
#define ALPHA 0.1f
#define BETA  0.9f
#define LEAKY 0.2f

#define RSH 8          // rows per bucket = 256
#define RB  256
#define BT  4096       // edges per bin tile
#define CAP 6400       // max edges per bucket segment
#define CMASK 0x1FFFF

// ---- zero an int array ----
__global__ __launch_bounds__(256) void zero_ints(int* __restrict__ p, int n) {
    int i = blockIdx.x * 256 + threadIdx.x;
    int st = gridDim.x * 256;
    for (; i < n; i += st) p[i] = 0;
}

// ---- fused: f1/f2 projections + fp32->fp16 convert of x; one wave per row ----
__global__ __launch_bounds__(256) void featconv(const float* __restrict__ x,
                                                const float* __restrict__ a,
                                                float* __restrict__ f1,
                                                float* __restrict__ f2,
                                                __half2* __restrict__ xh, int n) {
    int w = (blockIdx.x * blockDim.x + threadIdx.x) >> 6;
    int lane = threadIdx.x & 63;
    if (w >= n) return;
    const float2* xr = (const float2*)(x + (size_t)w * F);
    float2 v  = xr[lane];
    float2 A1 = ((const float2*)a)[lane];
    float2 A2 = ((const float2*)a)[64 + lane];
    float d1 = v.x * A1.x + v.y * A1.y;
    float d2 = v.x * A2.x + v.y * A2.y;
    for (int o = 32; o; o >>= 1) {
        d1 += __shfl_xor(d1, o);
        d2 += __shfl_xor(d2, o);
    }
    xh[(size_t)w * 64 + lane] = __float22half2_rn(v);
    if (lane == 0) { f1[w] = d1; f2[w] = d2; }
}

// ---- per-bucket edge histogram (LDS-staged) ----
__global__ __launch_bounds__(256) void bucket_hist(const int* __restrict__ erow,
                                                   int* __restrict__ bcnt, int e, int nb) {
    __shared__ int h[512];
    h[threadIdx.x] = 0; h[256 + threadIdx.x] = 0;
    __syncthreads();
    int i = blockIdx.x * 256 + threadIdx.x;
    int st = gridDim.x * 256;
    for (; i < e; i += st) atomicAdd(&h[erow[i] >> RSH], 1);
    __syncthreads();
    for (int b = threadIdx.x; b < nb; b += 256)
        if (h[b]) atomicAdd(&bcnt[b], h[b]);
}

// ---- scan bucket counts -> base & cursor (single block, pair Hillis-Steele) ----
__global__ __launch_bounds__(256) void bucket_scan(const int* __restrict__ bcnt,
                                                   int* __restrict__ base,
                                                   int* __restrict__ cursor,
                                                   int* __restrict__ rowptr_n,
                                                   int nb, int e) {
    __shared__ int arr[256];
    int t = threadIdx.x;
    int v0 = (2 * t     < nb) ? bcnt[2 * t]     : 0;
    int v1 = (2 * t + 1 < nb) ? bcnt[2 * t + 1] : 0;
    int ps = v0 + v1;
    arr[t] = ps; __syncthreads();
    for (int off = 1; off < 256; off <<= 1) {
        int add = (t >= off) ? arr[t - off] : 0;
        __syncthreads();
        arr[t] += add;
        __syncthreads();
    }
    int ex = arr[t] - ps;
    if (2 * t     <= nb) { base[2 * t]     = ex;      cursor[2 * t]     = ex; }
    if (2 * t + 1 <= nb) { base[2 * t + 1] = ex + v0; cursor[2 * t + 1] = ex + v0; }
    if (t == 255) *rowptr_n = e;
}

// ---- bin: write edges bucket-grouped (coalesced) as packed int2 ----
__global__ __launch_bounds__(256) void bin_edges(const int* __restrict__ erow,
                                                 const int* __restrict__ ecol,
                                                 const float* __restrict__ adj,
                                                 int* __restrict__ cursor,
                                                 int2* __restrict__ binned, int e) {
    __shared__ int tcnt[512], toff[512], res[512], tcur[512];
    __shared__ int arr[256];
    __shared__ short sidx[BT];
    int tid = threadIdx.x;
    int i0 = blockIdx.x * BT;
    int m = e - i0; if (m > BT) m = BT;
    tcnt[tid] = 0; tcnt[256 + tid] = 0;
    __syncthreads();
    for (int k = tid; k < m; k += 256) atomicAdd(&tcnt[erow[i0 + k] >> RSH], 1);
    __syncthreads();
    int v0 = tcnt[2 * tid], v1 = tcnt[2 * tid + 1];
    int ps = v0 + v1;
    arr[tid] = ps; __syncthreads();
    for (int off = 1; off < 256; off <<= 1) {
        int add = (tid >= off) ? arr[tid - off] : 0;
        __syncthreads();
        arr[tid] += add;
        __syncthreads();
    }
    int ex = arr[tid] - ps;
    toff[2 * tid] = ex; toff[2 * tid + 1] = ex + v0;
    __syncthreads();
    for (int b = tid; b < 512; b += 256) {
        if (tcnt[b] > 0) res[b] = atomicAdd(&cursor[b], tcnt[b]);
        tcur[b] = 0;
    }
    __syncthreads();
    for (int k = tid; k < m; k += 256) {
        int b = erow[i0 + k] >> RSH;
        int rk = atomicAdd(&tcur[b], 1);
        sidx[toff[b] + rk] = (short)k;
    }
    __syncthreads();
    for (int j = tid; j < m; j += 256) {
        int k = sidx[j];
        int i = i0 + k;
        int r = erow[i];
        int b = r >> RSH;
        int dst = res[b] + (j - toff[b]);
        binned[dst] = make_int2(((r & (RB - 1)) << 17) | ecol[i], __float_as_int(adj[i]));
    }
}

// ---- build: per-bucket CSR segment in LDS; rowptr, exp, s, rs — zero global atomics ----
__global__ __launch_bounds__(256) void build_csr(const int2* __restrict__ binned,
                                                 const int* __restrict__ bbase,
                                                 const float* __restrict__ f1,
                                                 const float* __restrict__ f2,
                                                 int2* __restrict__ csr,
                                                 int* __restrict__ rowptr,
                                                 float* __restrict__ sden,
                                                 float* __restrict__ rsg, int n) {
    int k = blockIdx.x;
    int row0 = k << RSH;
    int nr = n - row0; if (nr > RB) nr = RB;
    int m0 = bbase[k];
    int m = bbase[k + 1] - m0; if (m > CAP) m = CAP;
    int tid = threadIdx.x;
    __shared__ int   cnt[RB], cur[RB], rpl[RB], arr[256];
    __shared__ float f1l[RB], sl[RB], rsl[RB];
    __shared__ int2  seg[CAP];
    cnt[tid] = 0; cur[tid] = 0; sl[tid] = 0.f; rsl[tid] = 0.f;
    f1l[tid] = (tid < nr) ? f1[row0 + tid] : 0.f;
    __syncthreads();
    for (int t = tid; t < m; t += 256) atomicAdd(&cnt[(binned[m0 + t].x >> 17) & 0xFF], 1);
    __syncthreads();
    int v = cnt[tid];
    arr[tid] = v; __syncthreads();
    for (int off = 1; off < 256; off <<= 1) {
        int add = (tid >= off) ? arr[tid - off] : 0;
        __syncthreads();
        arr[tid] += add;
        __syncthreads();
    }
    rpl[tid] = arr[tid] - v;
    __syncthreads();
    if (tid < nr) rowptr[row0 + tid] = m0 + rpl[tid];
    for (int t = tid; t < m; t += 256) {
        int2 w = binned[m0 + t];
        int rl = (w.x >> 17) & 0xFF;
        int c  = w.x & CMASK;
        float tt = f1l[rl] + f2[c];
        tt = (tt >= 0.f) ? tt : LEAKY * tt;
        float exv = __expf(tt);
        int pos = atomicAdd(&cur[rl], 1);
        seg[rpl[rl] + pos] = make_int2(c, __float_as_int(exv));
        atomicAdd(&sl[rl], exv);
        atomicAdd(&rsl[rl], 0.5f * __int_as_float(w.y) * exv);
    }
    __syncthreads();
    for (int t = tid; t < m; t += 256) csr[m0 + t] = seg[t];
    if (tid < nr) { sden[row0 + tid] = sl[tid]; rsg[row0 + tid] = rsl[tid]; }
}

// ---- SpMM hop (fp16 gather, 16-deep batched, raw half2 regs); one wave per row ----
// final_hop == 0: writes g = acc/s as fp16 only.
// final_hop != 0: out = 0.001*x + 0.009*c0*g1 + 0.09*c1*g2 + 0.9*c2*g3
__global__ __launch_bounds__(256) void spmm_fuse(const __half2* __restrict__ upd_in,
                                                 __half2* __restrict__ upd_out,
                                                 const __half2* __restrict__ xh,
                                                 const __half2* __restrict__ g1h,
                                                 float* __restrict__ out,
                                                 const int2* __restrict__ csr,
                                                 const int* __restrict__ rowptr,
                                                 const float* __restrict__ sden,
                                                 const float* __restrict__ rs,
                                                 const float* __restrict__ cheb,
                                                 int n, int final_hop) {
    int r = blockIdx.x * 4 + (threadIdx.x >> 6);
    int lane = threadIdx.x & 63;
    if (r >= n) return;
    int sp = rowptr[r];
    int deg = rowptr[r + 1] - sp;

    float2 acc = make_float2(0.f, 0.f);
    for (int base = 0; base < deg; base += 64) {
        int mm = deg - base; if (mm > 64) mm = 64;
        // lanes >= mm hold (row 0, weight 0): padded gathers are cheap (L2-hot) and add 0
        int2 ed = (lane < mm) ? csr[sp + base + lane] : make_int2(0, 0);
        int mmB = (mm + 15) & ~15;
        for (int j = 0; j < mmB; j += 16) {
            __half2 g[16]; float u[16];
            #pragma unroll
            for (int kk = 0; kk < 16; kk++) {
                int c  = __shfl(ed.x, j + kk) & CMASK;
                u[kk]  = __int_as_float(__shfl(ed.y, j + kk));
                g[kk]  = upd_in[(size_t)c * 64 + lane];
            }
            #pragma unroll
            for (int kk = 0; kk < 16; kk++) {
                float2 f = __half22float2(g[kk]);
                acc.x += u[kk] * f.x;
                acc.y += u[kk] * f.y;
            }
        }
    }

    float sr = sden[r];
    float inv = (sr > 0.f) ? 1.f / sr : 0.f;
    float gx = acc.x * inv, gy = acc.y * inv;
    size_t idx = (size_t)r * 64 + lane;

    if (!final_hop) {
        upd_out[idx] = __float22half2_rn(make_float2(gx, gy));
    } else {
        float rsum = rs[r] * inv;
        float s0 = 1.f / (1.f + __expf(-cheb[0]));
        float s1 = 1.f / (1.f + __expf(-cheb[1]));
        float c0 = 1.f - BETA * rsum;
        float c1 = 1.f - BETA * rsum * s0;
        float c2 = 1.f - BETA * rsum * s0 * s1;
        float2 xv = __half22float2(xh[idx]);
        float2 g1 = __half22float2(g1h[idx]);
        float2 g2 = __half22float2(upd_in[idx]);
        float2 o;
        o.x = 0.001f * xv.x + 0.009f * c0 * g1.x + 0.09f * c1 * g2.x + 0.9f * c2 * gx;
        o.y = 0.001f * xv.y + 0.009f * c0 * g1.y + 0.09f * c1 * g2.y + 0.9f * c2 * gy;
        ((float2*)out)[idx] = o;
    }
}

extern "C" void kernel_launch(void* const* d_in, const int* in_sizes, int n_in,
                              void* d_out, int out_size, void* d_ws, size_t ws_size,
                              hipStream_t stream) {
    const float* x    = (const float*)d_in[0];
    const float* a    = (const float*)d_in[2];
    const float* cheb = (const float*)d_in[4];
    const float* adj  = (const float*)d_in[5];
    const int*   erow = (const int*)d_in[6];
    const int*   ecol = (const int*)d_in[7];
    int n = in_sizes[0] / F;
    int e = in_sizes[5];
    float* out = (float*)d_out;
    int nb = (n + RB - 1) >> RSH;

    // workspace layout (4-byte words)
    float* ws = (float*)d_ws;
    size_t NH = (size_t)n * 64;               // half2 words per feature buffer
    int2*    csr  = (int2*)ws;                // 2E words
    __half2* xh   = (__half2*)(ws + 2 * (size_t)e);
    __half2* u1h  = xh + NH;
    __half2* u2h  = u1h + NH;                 // binned aliases u2h (dead after build)
    int2*    binned = (int2*)u2h;
    float* f1     = (float*)(u2h + NH);
    float* f2     = f1 + n;
    float* sden   = f2 + n;
    float* rs     = sden + n;
    int*   rowptr = (int*)(rs + n);           // n+1
    int*   bcnt   = rowptr + n + 1;           // nb (≤512)
    int*   bbase  = bcnt + 512;               // nb+1
    int*   bcur   = bbase + 513;              // nb+1

    int wave_blocks = (n + 3) / 4;

    hipLaunchKernelGGL(zero_ints, dim3(4), dim3(256), 0, stream, bcnt, nb);
    hipLaunchKernelGGL(featconv, dim3(wave_blocks), dim3(256), 0, stream, x, a, f1, f2, xh, n);
    hipLaunchKernelGGL(bucket_hist, dim3(1024), dim3(256), 0, stream, erow, bcnt, e, nb);
    hipLaunchKernelGGL(bucket_scan, dim3(1), dim3(256), 0, stream, bcnt, bbase, bcur, rowptr + n, nb, e);
    hipLaunchKernelGGL(bin_edges, dim3((e + BT - 1) / BT), dim3(256), 0, stream,
                       erow, ecol, adj, bcur, binned, e);
    hipLaunchKernelGGL(build_csr, dim3(nb), dim3(256), 0, stream,
                       binned, bbase, f1, f2, csr, rowptr, sden, rs, n);

    // hop 0: g1 = norm(U) @ xh              (final_hop = 0)
    hipLaunchKernelGGL(spmm_fuse, dim3(wave_blocks), dim3(256), 0, stream,
                       xh, u1h, (const __half2*)nullptr, (const __half2*)nullptr,
                       (float*)nullptr, csr, rowptr, sden, rs, cheb, n, 0);
    // hop 1: g2 = norm(U) @ g1              (final_hop = 0)
    hipLaunchKernelGGL(spmm_fuse, dim3(wave_blocks), dim3(256), 0, stream,
                       u1h, u2h, (const __half2*)nullptr, (const __half2*)nullptr,
                       (float*)nullptr, csr, rowptr, sden, rs, cheb, n, 0);
    // hop 2: g3 gather + fused final epilogue (final_hop = 1)
    hipLaunchKernelGGL(spmm_fuse, dim3(wave_blocks), dim3(256), 0, stream,
                       u2h, (__half2*)nullptr, xh, u1h,
                       out, csr, rowptr, sden, rs, cheb, n, 1);
}